// Round 8
// baseline (219.370 us; speedup 1.0000x reference)
//
#include <hip/hip_runtime.h>
#include <hip/hip_fp16.h>

// ---------------------------------------------------------------------------
// SoftDecisionTreeEnsemble: N_TREES=15, DEPTH=3, INPUT_DIM=128, N_CLASSES=10
// R10 = R5 (best, 202.14us) + prep merged into tree_main WITHOUT touching
// register allocation (R3 lesson): each block cooperatively computes the
// packed weights into lds[1] (exactly 32KB: wq 28672 + wbT 4096; biases go
// straight to regs from params), barrier, bulk half8 reg-loads from LDS
// (same fragment pattern R5 used from global), barrier, then R5's loop
// verbatim (tile-1 DMA overwrites lds[1]; vmcnt ledger identical).
// Removes: prep dispatch + inter-dispatch gap + d_ws round-trip.
// Structure findings so far (R3..R9): resident-weight 8-tile chassis is
// fastest; pipeline depth / coalescing / conflicts / x-path / occupancy all
// falsified as dominant cost; x is half-L3-resident (R7 FETCH=67MB).
// ---------------------------------------------------------------------------

typedef float    f32x4 __attribute__((ext_vector_type(4)));
typedef _Float16 half8 __attribute__((ext_vector_type(8)));

#define TREES      15
#define IDIM       128
#define NCLS       10
#define NINT       7
#define NLVS       8
#define PER_TREE   (NINT*IDIM + NINT + NLVS*NCLS)   // 983
#define NODES      (TREES*NINT)                     // 105
#define NPAD       112                              // 7 n-tiles of 16
#define KPAD       128                              // leaf K padded
#define RSTR       272                              // s/leaf row stride bytes (136 halves)
#define NBLK       512                              // 2 blocks/CU

// DMA one wave-quarter (16 rows x 512B) of an x tile into LDS, LINEAR:
// lanes 0-31 read one contiguous 512B row (perfect coalescing), lanes 32-63
// the next row. LDS dest is lane-linear -> image is row-major [16][512B].
__device__ __forceinline__ void dma_quarter(const float* __restrict__ x,
                                            long grow0, char* qdst, int lane) {
    #pragma unroll
    for (int it = 0; it < 8; ++it) {
        int r = 2 * it + (lane >> 5);
        const float* gp = x + (grow0 + r) * IDIM + (lane & 31) * 4;
        __builtin_amdgcn_global_load_lds(
            (const __attribute__((address_space(1))) void*)gp,
            (__attribute__((address_space(3))) void*)(qdst + it * 1024),
            16, 0, 0);
    }
}

// ---------------------------------------------------------------------------
__global__ __launch_bounds__(256, 2) void tree_main(const float* __restrict__ x,
                                                    const float* __restrict__ p,
                                                    float* __restrict__ out,
                                                    int tpb) {
    __shared__ __align__(16) char lds[2][32768];

    const int tid  = threadIdx.x;
    const int lane = tid & 63;
    const int w    = tid >> 6;        // wave id: owns tile rows 16w..16w+15
    const int lm   = lane & 15;
    const int lq   = lane >> 4;
    const int rg   = lane >> 2;       // Phase B row (0..15)
    const int g    = lane & 3;        // Phase B tree group

    const long tile0 = (long)blockIdx.x * tpb;

    // prime: DMA tile 0 into lds[0] (overlaps the in-block prep below)
    dma_quarter(x, tile0 * 64 + 16 * w, &lds[0][w * 8192], lane);

    // ---- in-block prep into lds[1] (aliases tile-staging buffer 1) --------
    // wqs[112][128] f16 (row g=7t+n, zero-padded); wbs[16][128] f16:
    // wbs[c][8t+l] = softmax(leaf_logits[t][l])[c] * tw[t]. Zero padding is
    // load-bearing: padded nodes -> z=0 -> sigmoid 0.5; padded cols/classes
    // contribute 0. Total 28672 + 4096 = 32768 B exactly.
    _Float16* wqs = (_Float16*)&lds[1][0];
    _Float16* wbs = (_Float16*)&lds[1][28672];

    for (int i2 = tid; i2 < NPAD * IDIM; i2 += 256) {
        int g2 = i2 >> 7, k = i2 & 127;
        float v = 0.f;
        if (g2 < NODES) {
            int t = (g2 * 9363) >> 16;     // g2/7, exact for g2<=110
            int n = g2 - 7 * t;
            v = p[t * PER_TREE + n * IDIM + k];
        }
        wqs[i2] = (_Float16)v;
    }
    {
        const float* tl = p + TREES * PER_TREE;
        float m2 = tl[0];
        #pragma unroll
        for (int j = 1; j < TREES; ++j) m2 = fmaxf(m2, tl[j]);
        float s2 = 0.f;
        #pragma unroll
        for (int j = 0; j < TREES; ++j) s2 += __expf(tl[j] - m2);
        for (int i2 = tid; i2 < 16 * KPAD; i2 += 256) {
            int c = i2 >> 7, k = i2 & 127;
            float v = 0.f;
            if (c < NCLS && k < TREES * NLVS) {
                int t = k >> 3, l = k & 7;
                const float* ll = p + t * PER_TREE + NINT * IDIM + NINT + l * NCLS;
                float mx = ll[0];
                #pragma unroll
                for (int j = 1; j < NCLS; ++j) mx = fmaxf(mx, ll[j]);
                float se = 0.f;
                #pragma unroll
                for (int j = 0; j < NCLS; ++j) se += __expf(ll[j] - mx);
                float lsm = __expf(ll[c] - mx) / se;
                float tw  = __expf(tl[t] - m2) / s2;
                v = lsm * tw;
            }
            wbs[i2] = (_Float16)v;
        }
    }

    // biases straight to registers from params (simple gather; no LDS needed)
    float bb[7];
    #pragma unroll
    for (int nt = 0; nt < 7; ++nt) {
        int node = 16 * nt + lm;
        float v = 0.f;
        if (node < NODES) {
            int t = (node * 9363) >> 16;
            int n = node - 7 * t;
            v = p[t * PER_TREE + NINT * IDIM + n];
        }
        bb[nt] = v;
    }

    __syncthreads();                  // weights in LDS ready for all waves

    // resident weights: bulk half8 reg-loads from LDS (same fragment
    // pattern R5 used from global wq/wbT; keeps regalloc happy).
    half8 bf[7][4];
    #pragma unroll
    for (int nt = 0; nt < 7; ++nt)
        #pragma unroll
        for (int s = 0; s < 4; ++s)
            bf[nt][s] = *reinterpret_cast<const half8*>(wqs + (16 * nt + lm) * IDIM + 32 * s + 8 * lq);
    half8 wbf[4];
    #pragma unroll
    for (int s = 0; s < 4; ++s)
        wbf[s] = *reinterpret_cast<const half8*>(wbs + lm * KPAD + 32 * s + 8 * lq);

    __syncthreads();                  // all waves done reading lds[1]

    // drain tile-0 DMA + all prep global loads ONCE, then prime the second
    // prefetch slot (tile 1 overwrites the weight image in lds[1]).
    asm volatile("" ::: "memory");
    __builtin_amdgcn_s_waitcnt(0x0F70);           // vmcnt(0)
    asm volatile("" ::: "memory");
    if (tpb > 1)
        dma_quarter(x, (tile0 + 1) * 64 + 16 * w, &lds[1][w * 8192], lane);

    for (int i = 0; i < tpb; ++i) {
        char* qcur = &lds[i & 1][w * 8192];
        const long grow = (tile0 + i) * 64;      // global row of this tile

        // Counted wait for THIS tile's DMA (wave-private; no barrier).
        // In-order vm queue at top of iter i (D=8 DMA loads, st=4 stores):
        //   i==0 : tile 0 already drained above
        //   i==1 : [D1, D2, st0]                 -> need D1: vmcnt(12)
        //   steady: [Di, st(i-2), Di+1, st(i-1)] -> need Di: vmcnt(16)
        //   last  : [Dn-1, st(n-3), st(n-2)]     -> need Dn-1: vmcnt(8)
        asm volatile("" ::: "memory");
        if (i == 1)                __builtin_amdgcn_s_waitcnt(0x0F7C); // vmcnt(12)
        else if (i >= 2 && i < tpb - 1)
                                   __builtin_amdgcn_s_waitcnt(0x4F70); // vmcnt(16)
        else if (i == tpb - 1 && i >= 2)
                                   __builtin_amdgcn_s_waitcnt(0x0F78); // vmcnt(8)
        asm volatile("" ::: "memory");

        // ---- A-fragment gather from LINEAR LDS image + cvt to f16 ----
        half8 af[4];
        #pragma unroll
        for (int s = 0; s < 4; ++s) {
            int cc = 8 * s + 2 * lq;
            f32x4 f0 = *(const f32x4*)(qcur + lm * 512 + (cc       << 4));
            f32x4 f1 = *(const f32x4*)(qcur + lm * 512 + ((cc + 1) << 4));
            half8 a;
            #pragma unroll
            for (int j = 0; j < 4; ++j) {
                a[j]     = (_Float16)f0[j];
                a[j + 4] = (_Float16)f1[j];
            }
            af[s] = a;
        }

        // ---- Phase A: z-GEMM (bias in acc init) + sigmoid -> packed cols 8t+n
        #pragma unroll
        for (int nt = 0; nt < 7; ++nt) {
            f32x4 acc = {bb[nt], bb[nt], bb[nt], bb[nt]};
            #pragma unroll
            for (int s = 0; s < 4; ++s)
                acc = __builtin_amdgcn_mfma_f32_16x16x32_f16(af[s], bf[nt][s], acc, 0, 0, 0);
            int node = 16 * nt + lm;
            int col  = node + ((node * 9363) >> 16);   // node + node/7 = 8t+n
            #pragma unroll
            for (int r = 0; r < 4; ++r) {
                float z  = acc[r];                     // C/D: row=4lq+r, col=lm
                float sg = __builtin_amdgcn_rcpf(1.0f + __expf(-z));
                *(_Float16*)(qcur + (4 * lq + r) * RSTR + col * 2) = (_Float16)sg;
            }
        }

        // ---- Phase B: leaf probabilities (wave-lockstep, reads before writes)
        // b128 gather: tree t=4g+tt at halves [8t..8t+7] = byte 16t,
        // 16B-aligned since RSTR=272=17*16. Element 7 (col 8t+7) is never
        // written by Phase A and never used here.
        {
            const char* rowp = qcur + rg * RSTR;
            half8 hv[4];
            #pragma unroll
            for (int tt = 0; tt < 4; ++tt)
                hv[tt] = *(const half8*)(rowp + 64 * g + 16 * tt);
            half8 lv[4];
            #pragma unroll
            for (int tt = 0; tt < 4; ++tt) {
                float s0 = (float)hv[tt][0], s1 = (float)hv[tt][1], s2v = (float)hv[tt][2];
                float s3 = (float)hv[tt][3], s4 = (float)hv[tt][4], s5 = (float)hv[tt][5];
                float s6 = (float)hv[tt][6];
                float u1 = 1.f - s0, u2 = s0;
                float q1 = u1 * s1, q0 = u1 - q1;
                float q3 = u2 * s2v, q2 = u2 - q3;
                float L1 = q0 * s3, L0 = q0 - L1;
                float L3 = q1 * s4, L2 = q1 - L3;
                float L5 = q2 * s5, L4 = q2 - L5;
                float L7 = q3 * s6, L6 = q3 - L7;
                float m = (4 * g + tt < TREES) ? 1.f : 0.f;   // zero tree-15 slot
                half8 lv8;
                lv8[0] = (_Float16)(L0 * m); lv8[1] = (_Float16)(L1 * m);
                lv8[2] = (_Float16)(L2 * m); lv8[3] = (_Float16)(L3 * m);
                lv8[4] = (_Float16)(L4 * m); lv8[5] = (_Float16)(L5 * m);
                lv8[6] = (_Float16)(L6 * m); lv8[7] = (_Float16)(L7 * m);
                lv[tt] = lv8;
            }
            #pragma unroll
            for (int tt = 0; tt < 4; ++tt)
                *(half8*)(qcur + rg * RSTR + 64 * g + 16 * tt) = lv[tt];
        }

        // ---- Phase C: leaf x wbT MFMA -> out ----
        {
            half8 af2[4];
            #pragma unroll
            for (int s = 0; s < 4; ++s)
                af2[s] = *(const half8*)(qcur + lm * RSTR + 64 * s + 16 * lq);
            f32x4 a2 = {0.f, 0.f, 0.f, 0.f};
            #pragma unroll
            for (int s = 0; s < 4; ++s)
                a2 = __builtin_amdgcn_mfma_f32_16x16x32_f16(af2[s], wbf[s], a2, 0, 0, 0);

            // qcur fully consumed (af2 gather waited by the MFMA's lgkm):
            // DMA tile i+2 into this same buffer. Fences pin the issue point
            // between the Phase-C reads and the output stores so the vm
            // queue order is [.., D(i+2), st(i)].
            asm volatile("" ::: "memory");
            if (i + 2 < tpb)
                dma_quarter(x, (tile0 + i + 2) * 64 + 16 * w, qcur, lane);
            asm volatile("" ::: "memory");

            if (lm < NCLS) {
                #pragma unroll
                for (int r = 0; r < 4; ++r)
                    out[(grow + 16 * w + 4 * lq + r) * NCLS + lm] = a2[r];
            }
        }
    }
}

// ---------------------------------------------------------------------------
extern "C" void kernel_launch(void* const* d_in, const int* in_sizes, int n_in,
                              void* d_out, int out_size, void* d_ws, size_t ws_size,
                              hipStream_t stream) {
    const float* x      = (const float*)d_in[0];
    const float* params = (const float*)d_in[1];
    float* out = (float*)d_out;

    const int batch = in_sizes[0] / IDIM;      // 262144
    const int tiles = batch / 64;              // 4096
    const int tpb   = tiles / NBLK;            // 8

    tree_main<<<NBLK, 256, 0, stream>>>(x, params, out, tpb);
}

// Round 9
// 202.034 us; speedup vs baseline: 1.0858x; 1.0858x over previous
//
#include <hip/hip_runtime.h>
#include <hip/hip_fp16.h>

// ---------------------------------------------------------------------------
// SoftDecisionTreeEnsemble: N_TREES=15, DEPTH=3, INPUT_DIM=128, N_CLASSES=10
// R11 = R10 (single-dispatch, 84.5us tree_main) with its two measured
// regressions fixed:
//  1. weight image in lds[1] is now ROTATION-SWIZZLED (chunk' = (c+row)&15,
//     R9's proven scheme): the one-time bulk bf/wbf ds_read_b128s go from
//     16-way bank conflict (6.29M cycles, ~10us) to ~2-way (free).
//  2. prep vectorized: wqs written as half8 chunk-stores (7/thread, 8 scalar
//     f32 loads + cvt each), wbs as 1 chunk/thread -> serial prologue ~2-3us
//     instead of 5-10.
// Loop body = R5 verbatim (best chassis: 2-ahead DMA, counted vmcnt, linear
// x image, resident weights). Single dispatch saves ~7.5us fixed offset
// (measured: 134.9 vs 142.5).
// ---------------------------------------------------------------------------

typedef float    f32x4 __attribute__((ext_vector_type(4)));
typedef _Float16 half8 __attribute__((ext_vector_type(8)));

#define TREES      15
#define IDIM       128
#define NCLS       10
#define NINT       7
#define NLVS       8
#define PER_TREE   (NINT*IDIM + NINT + NLVS*NCLS)   // 983
#define NODES      (TREES*NINT)                     // 105
#define NPAD       112                              // 7 n-tiles of 16
#define KPAD       128                              // leaf K padded
#define RSTR       272                              // s/leaf row stride bytes (136 halves)
#define NBLK       512                              // 2 blocks/CU

// DMA one wave-quarter (16 rows x 512B) of an x tile into LDS, LINEAR:
// lanes 0-31 read one contiguous 512B row (perfect coalescing), lanes 32-63
// the next row. LDS dest is lane-linear -> image is row-major [16][512B].
__device__ __forceinline__ void dma_quarter(const float* __restrict__ x,
                                            long grow0, char* qdst, int lane) {
    #pragma unroll
    for (int it = 0; it < 8; ++it) {
        int r = 2 * it + (lane >> 5);
        const float* gp = x + (grow0 + r) * IDIM + (lane & 31) * 4;
        __builtin_amdgcn_global_load_lds(
            (const __attribute__((address_space(1))) void*)gp,
            (__attribute__((address_space(3))) void*)(qdst + it * 1024),
            16, 0, 0);
    }
}

// ---------------------------------------------------------------------------
__global__ __launch_bounds__(256, 2) void tree_main(const float* __restrict__ x,
                                                    const float* __restrict__ p,
                                                    float* __restrict__ out,
                                                    int tpb) {
    __shared__ __align__(16) char lds[2][32768];

    const int tid  = threadIdx.x;
    const int lane = tid & 63;
    const int w    = tid >> 6;        // wave id: owns tile rows 16w..16w+15
    const int lm   = lane & 15;
    const int lq   = lane >> 4;
    const int rg   = lane >> 2;       // Phase B row (0..15)
    const int g    = lane & 3;        // Phase B tree group

    const long tile0 = (long)blockIdx.x * tpb;

    // prime: DMA tile 0 into lds[0] (overlaps the in-block prep below)
    dma_quarter(x, tile0 * 64 + 16 * w, &lds[0][w * 8192], lane);

    // ---- in-block prep into lds[1], ROTATION-SWIZZLED ----------------------
    // wqs image: rows 0..111 (g=7t+n, zero-padded), 16 chunks of 16B per row,
    //   chunk c stored at slot (c+row)&15. addr(r,c) = r*256 + (((c+r)&15)<<4).
    // wbs image: rows 0..15 (class c), same rotation. 28672 + 4096 = 32768 B.
    // Zero padding is load-bearing: padded nodes -> z=0 -> sigmoid 0.5;
    // padded leaf cols/classes contribute 0.
    char* wqs = &lds[1][0];
    char* wbs = &lds[1][28672];

    // wqs: 1792 chunks, 7 per thread. 8 scalar f32 loads (params rows are
    // only 4B-aligned: PER_TREE=983 odd) + cvt + one half8 store.
    for (int cidx = tid; cidx < NPAD * 16; cidx += 256) {
        int r = cidx >> 4, c = cidx & 15;
        half8 h = {};
        if (r < NODES) {
            int t = (r * 9363) >> 16;      // r/7, exact for r<=110
            int n = r - 7 * t;
            const float* src = p + t * PER_TREE + n * IDIM + c * 8;
            #pragma unroll
            for (int j = 0; j < 8; ++j) h[j] = (_Float16)src[j];
        }
        *(half8*)(wqs + r * 256 + (((c + r) & 15) << 4)) = h;
    }
    // wbs: 256 chunks, 1 per thread.
    {
        const float* tl = p + TREES * PER_TREE;
        float m2 = tl[0];
        #pragma unroll
        for (int j = 1; j < TREES; ++j) m2 = fmaxf(m2, tl[j]);
        float s2 = 0.f;
        #pragma unroll
        for (int j = 0; j < TREES; ++j) s2 += __expf(tl[j] - m2);

        int r = tid >> 4, c = tid & 15;          // r = class row, c = chunk
        half8 h = {};
        if (r < NCLS) {
            #pragma unroll
            for (int j = 0; j < 8; ++j) {
                int k = c * 8 + j;               // 8t+l
                float v = 0.f;
                if (k < TREES * NLVS) {
                    int t = k >> 3, l = k & 7;
                    const float* ll = p + t * PER_TREE + NINT * IDIM + NINT + l * NCLS;
                    float mx = ll[0];
                    #pragma unroll
                    for (int q = 1; q < NCLS; ++q) mx = fmaxf(mx, ll[q]);
                    float se = 0.f;
                    #pragma unroll
                    for (int q = 0; q < NCLS; ++q) se += __expf(ll[q] - mx);
                    v = (__expf(ll[r] - mx) / se) * (__expf(tl[t] - m2) / s2);
                }
                h[j] = (_Float16)v;
            }
        }
        *(half8*)(wbs + r * 256 + (((c + r) & 15) << 4)) = h;
    }

    // biases straight to registers from params
    float bb[7];
    #pragma unroll
    for (int nt = 0; nt < 7; ++nt) {
        int node = 16 * nt + lm;
        float v = 0.f;
        if (node < NODES) {
            int t = (node * 9363) >> 16;
            int n = node - 7 * t;
            v = p[t * PER_TREE + NINT * IDIM + n];
        }
        bb[nt] = v;
    }

    __syncthreads();                  // weight image ready (drains DMA0 too)

    // resident weights: bulk half8 reg-loads from the swizzled image.
    // Fragment s of row r reads source chunk 4s+lq -> slot (4s+lq+r)&15;
    // r=16nt+lm -> slot (4s+lq+lm)&15: 2 lanes/16B-slot = conflict-free.
    half8 bf[7][4];
    #pragma unroll
    for (int nt = 0; nt < 7; ++nt)
        #pragma unroll
        for (int s = 0; s < 4; ++s)
            bf[nt][s] = *(const half8*)(wqs + (16 * nt + lm) * 256 + (((4 * s + lq + lm) & 15) << 4));
    half8 wbf[4];
    #pragma unroll
    for (int s = 0; s < 4; ++s)
        wbf[s] = *(const half8*)(wbs + lm * 256 + (((4 * s + lq + lm) & 15) << 4));

    __syncthreads();                  // all waves done reading lds[1]

    // tile-1 DMA may now overwrite the weight image.
    asm volatile("" ::: "memory");
    __builtin_amdgcn_s_waitcnt(0x0F70);           // vmcnt(0) (DMA0 long done)
    asm volatile("" ::: "memory");
    if (tpb > 1)
        dma_quarter(x, (tile0 + 1) * 64 + 16 * w, &lds[1][w * 8192], lane);

    for (int i = 0; i < tpb; ++i) {
        char* qcur = &lds[i & 1][w * 8192];
        const long grow = (tile0 + i) * 64;      // global row of this tile

        // Counted wait for THIS tile's DMA (wave-private; no barrier).
        // In-order vm queue at top of iter i (D=8 DMA loads, st=4 stores):
        //   i==0 : tile 0 drained at the barrier
        //   i==1 : [D1, D2, st0]                 -> need D1: vmcnt(12)
        //   steady: [Di, st(i-2), Di+1, st(i-1)] -> need Di: vmcnt(16)
        //   last  : [Dn-1, st(n-3), st(n-2)]     -> need Dn-1: vmcnt(8)
        asm volatile("" ::: "memory");
        if (i == 1)                __builtin_amdgcn_s_waitcnt(0x0F7C); // vmcnt(12)
        else if (i >= 2 && i < tpb - 1)
                                   __builtin_amdgcn_s_waitcnt(0x4F70); // vmcnt(16)
        else if (i == tpb - 1 && i >= 2)
                                   __builtin_amdgcn_s_waitcnt(0x0F78); // vmcnt(8)
        asm volatile("" ::: "memory");

        // ---- A-fragment gather from LINEAR LDS image + cvt to f16 ----
        half8 af[4];
        #pragma unroll
        for (int s = 0; s < 4; ++s) {
            int cc = 8 * s + 2 * lq;
            f32x4 f0 = *(const f32x4*)(qcur + lm * 512 + (cc       << 4));
            f32x4 f1 = *(const f32x4*)(qcur + lm * 512 + ((cc + 1) << 4));
            half8 a;
            #pragma unroll
            for (int j = 0; j < 4; ++j) {
                a[j]     = (_Float16)f0[j];
                a[j + 4] = (_Float16)f1[j];
            }
            af[s] = a;
        }

        // ---- Phase A: z-GEMM (bias in acc init) + sigmoid -> packed cols 8t+n
        #pragma unroll
        for (int nt = 0; nt < 7; ++nt) {
            f32x4 acc = {bb[nt], bb[nt], bb[nt], bb[nt]};
            #pragma unroll
            for (int s = 0; s < 4; ++s)
                acc = __builtin_amdgcn_mfma_f32_16x16x32_f16(af[s], bf[nt][s], acc, 0, 0, 0);
            int node = 16 * nt + lm;
            int col  = node + ((node * 9363) >> 16);   // node + node/7 = 8t+n
            #pragma unroll
            for (int r = 0; r < 4; ++r) {
                float z  = acc[r];                     // C/D: row=4lq+r, col=lm
                float sg = __builtin_amdgcn_rcpf(1.0f + __expf(-z));
                *(_Float16*)(qcur + (4 * lq + r) * RSTR + col * 2) = (_Float16)sg;
            }
        }

        // ---- Phase B: leaf probabilities (wave-lockstep, reads before writes)
        // b128 gather: tree t=4g+tt at halves [8t..8t+7] = byte 16t,
        // 16B-aligned since RSTR=272=17*16. Element 7 (col 8t+7) is never
        // written by Phase A and never used here.
        {
            const char* rowp = qcur + rg * RSTR;
            half8 hv[4];
            #pragma unroll
            for (int tt = 0; tt < 4; ++tt)
                hv[tt] = *(const half8*)(rowp + 64 * g + 16 * tt);
            half8 lv[4];
            #pragma unroll
            for (int tt = 0; tt < 4; ++tt) {
                float s0 = (float)hv[tt][0], s1 = (float)hv[tt][1], s2v = (float)hv[tt][2];
                float s3 = (float)hv[tt][3], s4 = (float)hv[tt][4], s5 = (float)hv[tt][5];
                float s6 = (float)hv[tt][6];
                float u1 = 1.f - s0, u2 = s0;
                float q1 = u1 * s1, q0 = u1 - q1;
                float q3 = u2 * s2v, q2 = u2 - q3;
                float L1 = q0 * s3, L0 = q0 - L1;
                float L3 = q1 * s4, L2 = q1 - L3;
                float L5 = q2 * s5, L4 = q2 - L5;
                float L7 = q3 * s6, L6 = q3 - L7;
                float m = (4 * g + tt < TREES) ? 1.f : 0.f;   // zero tree-15 slot
                half8 lv8;
                lv8[0] = (_Float16)(L0 * m); lv8[1] = (_Float16)(L1 * m);
                lv8[2] = (_Float16)(L2 * m); lv8[3] = (_Float16)(L3 * m);
                lv8[4] = (_Float16)(L4 * m); lv8[5] = (_Float16)(L5 * m);
                lv8[6] = (_Float16)(L6 * m); lv8[7] = (_Float16)(L7 * m);
                lv[tt] = lv8;
            }
            #pragma unroll
            for (int tt = 0; tt < 4; ++tt)
                *(half8*)(qcur + rg * RSTR + 64 * g + 16 * tt) = lv[tt];
        }

        // ---- Phase C: leaf x wbT MFMA -> out ----
        {
            half8 af2[4];
            #pragma unroll
            for (int s = 0; s < 4; ++s)
                af2[s] = *(const half8*)(qcur + lm * RSTR + 64 * s + 16 * lq);
            f32x4 a2 = {0.f, 0.f, 0.f, 0.f};
            #pragma unroll
            for (int s = 0; s < 4; ++s)
                a2 = __builtin_amdgcn_mfma_f32_16x16x32_f16(af2[s], wbf[s], a2, 0, 0, 0);

            // qcur fully consumed (af2 gather waited by the MFMA's lgkm):
            // DMA tile i+2 into this same buffer. Fences pin the issue point
            // between the Phase-C reads and the output stores so the vm
            // queue order is [.., D(i+2), st(i)].
            asm volatile("" ::: "memory");
            if (i + 2 < tpb)
                dma_quarter(x, (tile0 + i + 2) * 64 + 16 * w, qcur, lane);
            asm volatile("" ::: "memory");

            if (lm < NCLS) {
                #pragma unroll
                for (int r = 0; r < 4; ++r)
                    out[(grow + 16 * w + 4 * lq + r) * NCLS + lm] = a2[r];
            }
        }
    }
}

// ---------------------------------------------------------------------------
extern "C" void kernel_launch(void* const* d_in, const int* in_sizes, int n_in,
                              void* d_out, int out_size, void* d_ws, size_t ws_size,
                              hipStream_t stream) {
    const float* x      = (const float*)d_in[0];
    const float* params = (const float*)d_in[1];
    float* out = (float*)d_out;

    const int batch = in_sizes[0] / IDIM;      // 262144
    const int tiles = batch / 64;              // 4096
    const int tpb   = tiles / NBLK;            // 8

    tree_main<<<NBLK, 256, 0, stream>>>(x, params, out, tpb);
}